// Round 5
// baseline (993.271 us; speedup 1.0000x reference)
//
#include <hip/hip_runtime.h>
#include <math.h>

// FORCE / RLS, round 5: LDS-b128 matvec + split flags + atomic gsum.
//
// Block b owns state components j in [16b,16b+16). Wrec slice in LDS as
// float4[256][16] (4 rows interleaved) -> contiguous wave ds_read_b128.
// Cross-block per step: hglob (4 KB, UC stores/loads) + gsum (one float per
// history slot, accumulated with HW global_atomic_add_f32 at the LIC).
// Sync: per-block monotonic flag vectors; hflags published right after h
// stores drain (early), gflags after dot atomics drain. Consumers poll with
// one coalesced 64-lane load + ballot. gsum uses 4-deep rotation with
// distributed zeroing (zero at t+3 of a buffer read at t+1).
//
// Implicit-P math (P0 = I, wO0 = 0):
//   k_t = h_t - sum_{s<t} d_s k_s,  g_s = k_s.h_t,  d_s = c_s g_s
//   c_t = 1/(1+h.h - sum d_s g_s), z_t = -sum_{s<t} d_s e_s, e_t = z_t - y_t

#define NN   1024
#define TT   128
#define IDIM 16
#define ODIM 8
#define NBLK 64
#define NTHR 256
#define JPB  16
#define GST  136
#define KST  17

#define AL(p)    __hip_atomic_load((p), __ATOMIC_RELAXED, __HIP_MEMORY_SCOPE_AGENT)
#define AS(p, v) __hip_atomic_store((p), (v), __ATOMIC_RELAXED, __HIP_MEMORY_SCOPE_AGENT)

struct WS {
  unsigned hflags[NBLK];         // monotonic: block b published h of step f-1
  unsigned gflags[NBLK];         // monotonic: block b published dots of step f-1
  unsigned pad[128 - 2 * NBLK + 32];
  float gsum[4][GST];            // rotating dot accumulators (atomic fadd)
  float hglob[2][NN];            // parity-buffered h_t (UC)
};

__global__ __launch_bounds__(NTHR, 1) void force_rls_kernel(
    const float* __restrict__ x, const float* __restrict__ y,
    const float* __restrict__ Win, const float* __restrict__ Wrec,
    const float* __restrict__ Wfb, float* __restrict__ out, WS* ws)
{
  const int tid  = threadIdx.x;
  const int bid  = blockIdx.x;
  const int lane = tid & 63;
  const int wv   = tid >> 6;
  const int qq   = tid >> 4;     // 0..15
  const int jj   = tid & 15;
  const int j0   = bid * JPB;

  __shared__ float4 Wsl4[(NN / 4) * JPB];   // [rb][jj]: rows 4rb..4rb+3, col jj
  __shared__ float hfull[2][NN];
  __shared__ float Ksl[TT][KST];
  __shared__ float XW[TT][JPB];
  __shared__ float Ybuf[TT][ODIM];
  __shared__ float Ebuf[TT][ODIM];
  __shared__ float cbuf[TT], dbuf[TT];
  __shared__ float Wfb_s[ODIM][JPB];
  __shared__ float Winsl[IDIM][JPB];
  __shared__ float redM[4][JPB], redK[4][JPB];
  __shared__ float hcb[JPB];
  __shared__ float zbuf[ODIM];
  __shared__ float red2[4];
  __shared__ float sHH;
  __shared__ unsigned lcnt;

  // ---- init: stage Wrec slice into LDS (packed float4 rows) ----
#pragma unroll
  for (int m = 0; m < (NN * JPB) / NTHR; ++m) {   // 64 iters, coalesced global
    int e = m * NTHR + tid;
    int r = e >> 4, j = e & 15;
    ((float*)Wsl4)[(r >> 2) * 64 + j * 4 + (r & 3)] = Wrec[(size_t)r * NN + j0 + j];
  }
  Winsl[qq][jj] = Win[qq * NN + j0 + jj];
  if (tid < ODIM * JPB) Wfb_s[tid >> 4][tid & 15] = Wfb[(tid >> 4) * NN + j0 + (tid & 15)];
#pragma unroll
  for (int m = 0; m < (TT * ODIM) / NTHR; ++m) {
    int e = m * NTHR + tid; Ybuf[e >> 3][e & 7] = y[e];
  }
  if (tid < ODIM) zbuf[tid] = 0.f;
  if (tid == 0) lcnt = 0u;
  __syncthreads();
#pragma unroll
  for (int m = 0; m < (TT * JPB) / NTHR; ++m) {
    int e = m * NTHR + tid; int t = e >> 4, j = e & 15;
    float s = 0.f;
#pragma unroll
    for (int i = 0; i < IDIM; ++i) s += x[t * IDIM + i] * Winsl[i][j];
    XW[t][j] = s;
  }
  __syncthreads();

  float a_reg = 0.f;   // wave 0, lanes<16

  for (int t = 0; t < TT; ++t) {
    const int tau = t - 1;
    const int ph = t & 1;
    float hr0 = 0.f, hr1 = 0.f, hr2 = 0.f, hr3 = 0.f;
    float gval = 0.f;

    // ---- P0: poll h, issue h loads; poll g, issue g load ----
    if (t >= 1) {
      const unsigned tgt = (unsigned)t;
      while (true) {
        unsigned fv = AL(&ws->hflags[lane]);
        if (__ballot(fv >= tgt) == ~0ull) break;
        __builtin_amdgcn_s_sleep(1);
      }
      const float* hg = ws->hglob[ph ^ 1];
      hr0 = AL(&hg[4 * tid + 0]);
      hr1 = AL(&hg[4 * tid + 1]);
      hr2 = AL(&hg[4 * tid + 2]);
      hr3 = AL(&hg[4 * tid + 3]);
      while (true) {
        unsigned fv = AL(&ws->gflags[lane]);
        if (__ballot(fv >= tgt) == ~0ull) break;
        __builtin_amdgcn_s_sleep(1);
      }
      if (tid <= tau) gval = AL(&ws->gsum[tau & 3][tid]);
      ((float4*)hfull[ph])[tid] = make_float4(hr0, hr1, hr2, hr3);
    }
    __syncthreads();                                   // S1

    // ---- P2: matvec (b128) + scalar partials ----
    if (t >= 1) {
      const float4* hf4 = (const float4*)hfull[ph];
      const int base = qq * 16 + jj;                   // contiguous over wave
      float mp = 0.f;
#pragma unroll
      for (int i = 0; i < 16; ++i) {
        const float4 w4 = Wsl4[base + (i << 8)];
        const float4 hv = hf4[qq + (i << 4)];
        mp += w4.x * hv.x + w4.y * hv.y + w4.z * hv.z + w4.w * hv.w;
      }
      mp += __shfl_xor(mp, 16, 64);
      mp += __shfl_xor(mp, 32, 64);
      if (lane < 16) redM[wv][lane] = mp;

      float dval = 0.f;
      if (tid < tau) { dval = cbuf[tid] * gval; dbuf[tid] = dval; }
      else if (tid == tau) sHH = gval;
      float s1p = dval * gval;
      s1p += __shfl_xor(s1p, 1, 64);
      s1p += __shfl_xor(s1p, 2, 64);
      s1p += __shfl_xor(s1p, 4, 64);
      s1p += __shfl_xor(s1p, 8, 64);
      s1p += __shfl_xor(s1p, 16, 64);
      s1p += __shfl_xor(s1p, 32, 64);
      if (lane == 0) red2[wv] = s1p;
    }
    __syncthreads();                                   // S2

    // ---- P3: K partials (all waves); wave 0: c, z, state, h publish ----
    float h_own = 0.f;                                 // wave0 lanes<16
    if (t >= 1) {
      float kp = 0.f;
      for (int s = qq; s < tau; s += 16) kp -= dbuf[s] * Ksl[s][jj];
      kp += __shfl_xor(kp, 16, 64);
      kp += __shfl_xor(kp, 32, 64);
      if (lane < 16) redK[wv][lane] = kp;
    }
    if (wv == 0) {
      if (t >= 1) {
        if (lane == 0)
          cbuf[tau] = 1.f / (1.f + sHH - (red2[0] + red2[1] + red2[2] + red2[3]));
        const int o = lane & 7, g8 = lane >> 3;
        float zp = 0.f;
        for (int s = g8; s < tau; s += 8) zp += dbuf[s] * Ebuf[s][o];
        zp += __shfl_xor(zp, 8, 64);
        zp += __shfl_xor(zp, 16, 64);
        zp += __shfl_xor(zp, 32, 64);
        if (lane < 8) {
          float z = -zp;
          zbuf[o] = z;
          Ebuf[tau][o] = z - Ybuf[tau][o];
          if (bid == 0) out[tau * ODIM + o] = z;
        }
        if (lane < 16) {
          float acc = redM[0][lane] + redM[1][lane] + redM[2][lane] + redM[3][lane];
          float fb = 0.f;
#pragma unroll
          for (int o2 = 0; o2 < ODIM; ++o2) fb += zbuf[o2] * Wfb_s[o2][lane];
          a_reg = 0.9f * a_reg + 0.1f * (acc + XW[t][lane] + fb);
          h_own = tanhf(a_reg);
          hcb[lane] = h_own;
          AS(&ws->hglob[ph][j0 + lane], h_own);
        }
      } else {
        if (lane < 16) {
          a_reg = 0.1f * XW[0][lane];
          h_own = tanhf(a_reg);
          hcb[lane] = h_own;
          AS(&ws->hglob[0][j0 + lane], h_own);
        }
      }
      asm volatile("s_waitcnt vmcnt(0)" ::: "memory");
      if (lane == 0) AS(&ws->hflags[bid], (unsigned)(t + 1));   // early h flag
    }
    __syncthreads();                                   // S3

    // ---- P4: dots -> atomic gsum; K[tau] finalize; zero-duty ----
    if (wv == 0) {
      float kv = 0.f, hv2 = 0.f;
      if (lane < 16) {
        hv2 = h_own * h_own;
        if (t >= 1) {
          float kacc = hfull[ph][j0 + lane]
                     + redK[0][lane] + redK[1][lane] + redK[2][lane] + redK[3][lane];
          Ksl[tau][lane] = kacc;
          kv = kacc * h_own;
        }
      }
      kv  += __shfl_xor(kv, 1, 64);  hv2 += __shfl_xor(hv2, 1, 64);
      kv  += __shfl_xor(kv, 2, 64);  hv2 += __shfl_xor(hv2, 2, 64);
      kv  += __shfl_xor(kv, 4, 64);  hv2 += __shfl_xor(hv2, 4, 64);
      kv  += __shfl_xor(kv, 8, 64);  hv2 += __shfl_xor(hv2, 8, 64);
      if (lane == 0) {
        if (t >= 1) unsafeAtomicAdd(&ws->gsum[t & 3][tau], kv);
        unsafeAtomicAdd(&ws->gsum[t & 3][t], hv2);
      }
    } else {
      const int s = tid - 64;
      if (s <= t - 2) {
        float gp2 = 0.f;
#pragma unroll
        for (int j = 0; j < JPB; ++j) gp2 += Ksl[s][j] * hcb[j];
        unsafeAtomicAdd(&ws->gsum[t & 3][s], gp2);
      }
      if (tid == 64) {                                 // zero-duty: buf (t+2)&3
        const int zb = (t + 2) & 3;
        AS(&ws->gsum[zb][bid], 0.f);
        AS(&ws->gsum[zb][bid + 64], 0.f);
        if (bid < GST - 128) AS(&ws->gsum[zb][bid + 128], 0.f);
      }
    }
    asm volatile("s_waitcnt vmcnt(0)" ::: "memory");
    if (lane == 0) {
      unsigned old = atomicAdd(&lcnt, 1u);
      if (old == (unsigned)(4 * t + 3)) AS(&ws->gflags[bid], (unsigned)(t + 1));
    }
  }

  // ---- epilogue: z_{TT-1} (block 0) ----
  if (bid == 0) {
    const unsigned tgt = (unsigned)TT;
    while (true) {
      unsigned fv = AL(&ws->gflags[lane]);
      if (__ballot(fv >= tgt) == ~0ull) break;
      __builtin_amdgcn_s_sleep(1);
    }
    const int tau = TT - 1;
    if (tid < tau) dbuf[tid] = cbuf[tid] * AL(&ws->gsum[tau & 3][tid]);
    __syncthreads();
    if (wv == 0) {
      const int o = lane & 7, g8 = lane >> 3;
      float zp = 0.f;
      for (int s = g8; s < tau; s += 8) zp += dbuf[s] * Ebuf[s][o];
      zp += __shfl_xor(zp, 8, 64);
      zp += __shfl_xor(zp, 16, 64);
      zp += __shfl_xor(zp, 32, 64);
      if (lane < 8) out[tau * ODIM + o] = -zp;
    }
  }
}

extern "C" void kernel_launch(void* const* d_in, const int* in_sizes, int n_in,
                              void* d_out, int out_size, void* d_ws, size_t ws_size,
                              hipStream_t stream) {
  const float* x    = (const float*)d_in[0];
  const float* y    = (const float*)d_in[1];
  const float* Win  = (const float*)d_in[2];
  const float* Wrec = (const float*)d_in[3];
  const float* Wfb  = (const float*)d_in[4];
  // d_in[5] = wO (zeros), d_in[6] = P (identity): folded into implicit-P math.
  float* out = (float*)d_out;
  WS* ws = (WS*)d_ws;

  // Zero flags + gsum buffers (everything before hglob).
  hipMemsetAsync(d_ws, 0, offsetof(WS, hglob), stream);
  force_rls_kernel<<<NBLK, NTHR, 0, stream>>>(x, y, Win, Wrec, Wfb, out, ws);
}

// Round 6
// 852.566 us; speedup vs baseline: 1.1650x; 1.1650x over previous
//
#include <hip/hip_runtime.h>
#include <math.h>

// FORCE / RLS, round 6: tagged-data hops ("the data is the flag").
//
// Block b owns state j in [16b,16b+16). All cross-block values move as
// 8-byte (float,val | uint,tag) pairs via UC (sc0 sc1) dwordx2 stores —
// atomic at the LIC, no tearing. Consumers poll the data until tag == t.
// No flags, no vmcnt drains, no atomics, no memset (valid tags are 1..128;
// 0xAA poison / zeros never match). Parity-2 buffers safe: producer
// overwrites at t+2 only after detecting all blocks' t+1 data, which
// data-depends on their t reads (tag-poll = transitive barrier).
//
// Implicit-P math (P0 = I, wO0 = 0):
//   k_t = h_t - sum_{s<t} d_s k_s,  g_s = k_s.h_t,  d_s = c_s g_s
//   c_t = 1/(1+h.h - sum d_s g_s), z_t = -sum_{s<t} d_s e_s, e_t = z_t - y_t

#define NN   1024
#define TT   128
#define IDIM 16
#define ODIM 8
#define NBLK 64
#define NTHR 256
#define JPB  16
#define GSLOT 136
#define KST  17

typedef unsigned long long u64;

#define AL64(p)    __hip_atomic_load((p), __ATOMIC_RELAXED, __HIP_MEMORY_SCOPE_AGENT)
#define AS64(p, v) __hip_atomic_store((p), (v), __ATOMIC_RELAXED, __HIP_MEMORY_SCOPE_AGENT)

struct WS {
  u64 hpair[2][NN];          // (h, tag) parity-buffered
  u64 gpair[2][GSLOT][NBLK]; // (dot, tag): row s = 64 contiguous block entries
};

__device__ __forceinline__ u64 pk(float v, unsigned tag) {
  return ((u64)tag << 32) | (u64)__float_as_uint(v);
}
__device__ __forceinline__ float pv(u64 p) { return __uint_as_float((unsigned)p); }
__device__ __forceinline__ unsigned ptag(u64 p) { return (unsigned)(p >> 32); }

__global__ __launch_bounds__(NTHR, 1) void force_rls_kernel(
    const float* __restrict__ x, const float* __restrict__ y,
    const float* __restrict__ Win, const float* __restrict__ Wrec,
    const float* __restrict__ Wfb, float* __restrict__ out, WS* ws)
{
  const int tid  = threadIdx.x;
  const int bid  = blockIdx.x;
  const int lane = tid & 63;
  const int wv   = tid >> 6;
  const int qq   = tid >> 4;
  const int jj   = tid & 15;
  const int j0   = bid * JPB;
  const int sF   = tid & 127, hf = tid >> 7, b0 = hf * 32;

  __shared__ float4 Wsl4[(NN / 4) * JPB];  // 64 KB, packed for b128 matvec
  __shared__ float hfull[NN];
  __shared__ float Ksl[TT][KST];
  __shared__ float XW[TT][JPB];
  __shared__ float Ybuf[TT][ODIM];
  __shared__ float Ebuf[TT][ODIM];
  __shared__ float cbuf[TT];
  __shared__ float Wfb_s[ODIM][JPB];
  __shared__ float Winsl[IDIM][JPB];
  __shared__ float redM[4][JPB], redK[4][JPB];
  __shared__ float redG[2][TT];
  __shared__ float hcb[JPB];
  __shared__ float zbuf[ODIM];
  __shared__ float red2[4];
  __shared__ float sHH;

  // ---- init: stage reused data into LDS ----
#pragma unroll
  for (int m = 0; m < (NN * JPB) / NTHR; ++m) {
    int e = m * NTHR + tid;
    int r = e >> 4, j = e & 15;
    ((float*)Wsl4)[(r >> 2) * 64 + j * 4 + (r & 3)] = Wrec[(size_t)r * NN + j0 + j];
  }
  Winsl[qq][jj] = Win[qq * NN + j0 + jj];
  if (tid < ODIM * JPB) Wfb_s[tid >> 4][tid & 15] = Wfb[(tid >> 4) * NN + j0 + (tid & 15)];
#pragma unroll
  for (int m = 0; m < (TT * ODIM) / NTHR; ++m) {
    int e = m * NTHR + tid; Ybuf[e >> 3][e & 7] = y[e];
  }
  __syncthreads();
#pragma unroll
  for (int m = 0; m < (TT * JPB) / NTHR; ++m) {
    int e = m * NTHR + tid; int t = e >> 4, j = e & 15;
    float s = 0.f;
#pragma unroll
    for (int i = 0; i < IDIM; ++i) s += x[t * IDIM + i] * Winsl[i][j];
    XW[t][j] = s;
  }
  __syncthreads();

  float a_reg = 0.f;   // wave 0, lanes<16

  for (int t = 0; t < TT; ++t) {
    const int tau = t - 1;
    const int ph = t & 1;

    // ---- P0: poll h (tag==t), stage; poll g column (tag==t), partial-sum ----
    if (t >= 1) {
      const u64* hp = &ws->hpair[ph ^ 1][4 * tid];
      u64 a0, a1, a2, a3;
      while (true) {
        a0 = AL64(hp + 0); a1 = AL64(hp + 1);
        a2 = AL64(hp + 2); a3 = AL64(hp + 3);
        if (ptag(a0) == (unsigned)t && ptag(a1) == (unsigned)t &&
            ptag(a2) == (unsigned)t && ptag(a3) == (unsigned)t) break;
        __builtin_amdgcn_s_sleep(1);
      }
      ((float4*)hfull)[tid] = make_float4(pv(a0), pv(a1), pv(a2), pv(a3));
      if (sF <= tau) {
        const u64* gp = &ws->gpair[ph ^ 1][sF][b0];   // 32 contiguous pairs
        u64 v[32];
        while (true) {
          bool ok = true;
#pragma unroll
          for (int b = 0; b < 32; ++b) v[b] = AL64(gp + b);
#pragma unroll
          for (int b = 0; b < 32; ++b) ok &= (ptag(v[b]) == (unsigned)t);
          if (ok) break;
          __builtin_amdgcn_s_sleep(1);
        }
        float g = 0.f;
#pragma unroll
        for (int b = 0; b < 32; ++b) g += pv(v[b]);
        redG[hf][sF] = g;
      }
    }
    __syncthreads();                                   // S1

    // ---- P2: matvec + K-partials + scalar partials + z (wave0) ----
    if (t >= 1) {
      const float4* hf4 = (const float4*)hfull;
      const int base = qq * 16 + jj;
      float mp = 0.f;
#pragma unroll
      for (int i = 0; i < 16; ++i) {
        const float4 w4 = Wsl4[base + (i << 8)];
        const float4 hv = hf4[qq + (i << 4)];
        mp += w4.x * hv.x + w4.y * hv.y + w4.z * hv.z + w4.w * hv.w;
      }
      mp += __shfl_xor(mp, 16, 64);
      mp += __shfl_xor(mp, 32, 64);
      if (lane < 16) redM[wv][lane] = mp;

      // K[tau] partials: d_s recomputed on the fly (no dbuf)
      float kp = 0.f;
      for (int s = qq; s < tau; s += 16)
        kp -= cbuf[s] * (redG[0][s] + redG[1][s]) * Ksl[s][jj];
      kp += __shfl_xor(kp, 16, 64);
      kp += __shfl_xor(kp, 32, 64);
      if (lane < 16) redK[wv][lane] = kp;

      // s1 partial: sum_s d_s g_s
      float dval = 0.f, gval = 0.f;
      if (tid <= tau) {
        gval = redG[0][tid] + redG[1][tid];
        if (tid < tau) dval = cbuf[tid] * gval;
        else sHH = gval;
      }
      float s1p = dval * gval;
      s1p += __shfl_xor(s1p, 1, 64);
      s1p += __shfl_xor(s1p, 2, 64);
      s1p += __shfl_xor(s1p, 4, 64);
      s1p += __shfl_xor(s1p, 8, 64);
      s1p += __shfl_xor(s1p, 16, 64);
      s1p += __shfl_xor(s1p, 32, 64);
      if (lane == 0) red2[wv] = s1p;

      if (wv == 0) {                                   // z_{tau}
        const int o = lane & 7, g8 = lane >> 3;
        float zp = 0.f;
        for (int s = g8; s < tau; s += 8)
          zp += cbuf[s] * (redG[0][s] + redG[1][s]) * Ebuf[s][o];
        zp += __shfl_xor(zp, 8, 64);
        zp += __shfl_xor(zp, 16, 64);
        zp += __shfl_xor(zp, 32, 64);
        if (lane < 8) {
          float z = -zp;
          zbuf[o] = z;
          Ebuf[tau][o] = z - Ybuf[tau][o];
          if (bid == 0) out[tau * ODIM + o] = z;
        }
      }
    }
    __syncthreads();                                   // S2

    // ---- P3 (wave0): c_tau, state, publish h; K finalize, publish own dots ----
    if (wv == 0) {
      if (t >= 1 && lane == 0)
        cbuf[tau] = 1.f / (1.f + sHH - (red2[0] + red2[1] + red2[2] + red2[3]));
      float h_own = 0.f;
      if (lane < 16) {
        if (t >= 1) {
          float acc = redM[0][lane] + redM[1][lane] + redM[2][lane] + redM[3][lane];
          float fb = 0.f;
#pragma unroll
          for (int o = 0; o < ODIM; ++o) fb += zbuf[o] * Wfb_s[o][lane];
          a_reg = 0.9f * a_reg + 0.1f * (acc + XW[t][lane] + fb);
        } else {
          a_reg = 0.1f * XW[0][lane];
        }
        h_own = tanhf(a_reg);
        hcb[lane] = h_own;
        AS64(&ws->hpair[ph][j0 + lane], pk(h_own, (unsigned)(t + 1)));
      }
      float kv = 0.f, hv2 = 0.f;
      if (lane < 16) {
        hv2 = h_own * h_own;
        if (t >= 1) {
          float kacc = hfull[j0 + lane]
                     + redK[0][lane] + redK[1][lane] + redK[2][lane] + redK[3][lane];
          Ksl[tau][lane] = kacc;
          kv = kacc * h_own;
        }
      }
      kv  += __shfl_xor(kv, 1, 64);  hv2 += __shfl_xor(hv2, 1, 64);
      kv  += __shfl_xor(kv, 2, 64);  hv2 += __shfl_xor(hv2, 2, 64);
      kv  += __shfl_xor(kv, 4, 64);  hv2 += __shfl_xor(hv2, 4, 64);
      kv  += __shfl_xor(kv, 8, 64);  hv2 += __shfl_xor(hv2, 8, 64);
      if (lane == 0) {
        if (t >= 1) AS64(&ws->gpair[ph][tau][bid], pk(kv, (unsigned)(t + 1)));
        AS64(&ws->gpair[ph][t][bid], pk(hv2, (unsigned)(t + 1)));
      }
    }
    __syncthreads();                                   // S3

    // ---- P4 (waves 1-3): history dots, publish ----
    if (wv > 0) {
      const int s = tid - 64;
      if (s <= t - 2) {
        float gp = 0.f;
#pragma unroll
        for (int j = 0; j < JPB; ++j) gp += Ksl[s][j] * hcb[j];
        AS64(&ws->gpair[ph][s][bid], pk(gp, (unsigned)(t + 1)));
      }
    }
    // no sync: next P0 polls externally; LDS hazards ordered by S1/S2 of t+1
  }

  // ---- epilogue: z_{TT-1} (block 0) ----
  if (bid == 0) {
    const int tau = TT - 1;
    const int pe = tau & 1;
    {
      const u64* gp = &ws->gpair[pe][sF][b0];
      u64 v[32];
      while (true) {
        bool ok = true;
#pragma unroll
        for (int b = 0; b < 32; ++b) v[b] = AL64(gp + b);
#pragma unroll
        for (int b = 0; b < 32; ++b) ok &= (ptag(v[b]) == (unsigned)TT);
        if (ok) break;
        __builtin_amdgcn_s_sleep(1);
      }
      float g = 0.f;
#pragma unroll
      for (int b = 0; b < 32; ++b) g += pv(v[b]);
      redG[hf][sF] = g;
    }
    __syncthreads();
    if (wv == 0) {
      const int o = lane & 7, g8 = lane >> 3;
      float zp = 0.f;
      for (int s = g8; s < tau; s += 8)
        zp += cbuf[s] * (redG[0][s] + redG[1][s]) * Ebuf[s][o];
      zp += __shfl_xor(zp, 8, 64);
      zp += __shfl_xor(zp, 16, 64);
      zp += __shfl_xor(zp, 32, 64);
      if (lane < 8) out[tau * ODIM + o] = -zp;
    }
  }
}

extern "C" void kernel_launch(void* const* d_in, const int* in_sizes, int n_in,
                              void* d_out, int out_size, void* d_ws, size_t ws_size,
                              hipStream_t stream) {
  const float* x    = (const float*)d_in[0];
  const float* y    = (const float*)d_in[1];
  const float* Win  = (const float*)d_in[2];
  const float* Wrec = (const float*)d_in[3];
  const float* Wfb  = (const float*)d_in[4];
  // d_in[5] = wO (zeros), d_in[6] = P (identity): folded into implicit-P math.
  float* out = (float*)d_out;
  WS* ws = (WS*)d_ws;

  // Defensive: clear tag space (valid tags 1..128; poison/zeros never match,
  // but don't rely on the harness's poison pattern).
  hipMemsetAsync(d_ws, 0, sizeof(WS), stream);
  force_rls_kernel<<<NBLK, NTHR, 0, stream>>>(x, y, Win, Wrec, Wfb, out, ws);
}